// Round 8
// baseline (713.338 us; speedup 1.0000x reference)
//
#include <hip/hip_runtime.h>

typedef __attribute__((ext_vector_type(8))) __bf16 bf16x8;
typedef __attribute__((ext_vector_type(4))) float floatx4;
typedef __attribute__((ext_vector_type(8))) unsigned short ushort8v;
typedef __attribute__((ext_vector_type(4))) unsigned short ushort4v;

namespace {
constexpr int kNU = 100000, kNI = 100000, kE = 600000;
constexpr int kFU = 96, kFI = 160, kH = 128, kOUT = 64;
constexpr float kEPS = 1e-5f;
constexpr int kM = 32;                 // rows per block in MFMA kernels
constexpr int kNCHUNK = 98;            // ceil(100000 / 1024)
constexpr int kNBLK = kNU / kM;        // 3125 row-blocks per node type
constexpr int kEB = (kE + 255) / 256;  // 2344 edge-slices
constexpr int kPART = kNU / 8;         // dst-id range per XCD partition
}

__device__ __forceinline__ unsigned short f2b(float f) {  // fp32 -> bf16 RNE
  unsigned u = __builtin_bit_cast(unsigned, f);
  u += 0x7FFFu + ((u >> 16) & 1u);
  return (unsigned short)(u >> 16);
}
__device__ __forceinline__ float b2f(unsigned short h) {
  return __builtin_bit_cast(float, (unsigned)h << 16);
}
// 3-way bf16 split: v = h + m + l, residual <= ~2^-27 |v|
__device__ __forceinline__ void split3(float v, unsigned short& h,
                                       unsigned short& m, unsigned short& l) {
  h = f2b(v);
  const float r1 = v - b2f(h);   // exact
  m = f2b(r1);
  const float r2 = r1 - b2f(m);  // exact
  l = f2b(r2);
}
// 2-way bf16 split: v = h + m, residual <= ~2^-18 |v|
__device__ __forceinline__ void split2(float v, unsigned short& h,
                                       unsigned short& m) {
  h = f2b(v);
  m = f2b(v - b2f(h));
}
__device__ __forceinline__ bf16x8 ldb8(const unsigned short* p) {
  return __builtin_bit_cast(bf16x8, *(const ushort8v*)p);
}
__device__ __forceinline__ floatx4 mfma16(bf16x8 a, bf16x8 b, floatx4 c) {
  return __builtin_amdgcn_mfma_f32_16x16x32_bf16(a, b, c, 0, 0, 0);
}
// Swizzled LDS accessor (bf16 planes): plane stride 8 KB, row stride 256 B
__device__ __forceinline__ unsigned short* ab_ptr(void* base, int plane, int r,
                                                  int bo) {
  return (unsigned short*)((char*)base + plane * 8192 + r * 256 +
                           (bo ^ ((r & 7) << 4)));
}
// Async HBM -> LDS, 16 B per lane (lds dest = base + lane*16)
__device__ __forceinline__ void gload_lds16(const void* g, void* l) {
  __builtin_amdgcn_global_load_lds(
      (const __attribute__((address_space(1))) void*)g,
      (__attribute__((address_space(3))) void*)l, 16, 0, 0);
}
// split 8 fp32 (two float4) into h/m bf16x8 pair
__device__ __forceinline__ void split8(const float4& x, const float4& y,
                                       bf16x8& h8, bf16x8& m8) {
  ushort8v h, m;
  const float* p0 = &x.x;
  const float* p1 = &y.x;
#pragma unroll
  for (int u = 0; u < 4; ++u) {
    unsigned short th, tm;
    split2(p0[u], th, tm);
    h[u] = th; m[u] = tm;
    split2(p1[u], th, tm);
    h[4 + u] = th; m[4 + u] = tm;
  }
  h8 = __builtin_bit_cast(bf16x8, h);
  m8 = __builtin_bit_cast(bf16x8, m);
}

// --- weight convert+transpose+3-split: Wh/Wm/Wl[n][k] = split(W[k][n]) ------
struct WcvtArgs {
  const float* src[10];
  unsigned short* dh[10];
  unsigned short* dm[10];
  unsigned short* dl[10];
  int K[10], N[10];
};
__global__ __launch_bounds__(256) void wcvt(WcvtArgs a) {
  const int m = blockIdx.y;
  const int K = a.K[m], N = a.N[m];
  const int idx = blockIdx.x * 256 + threadIdx.x;
  if (idx < K * N) {
    const int n = idx / K, k = idx - n * K;
    unsigned short h, mm, l;
    split3(a.src[m][(size_t)k * N + n], h, mm, l);
    a.dh[m][idx] = h;
    a.dm[m][idx] = mm;
    a.dl[m][idx] = l;
  }
}

// ---------------- CSR build -------------------------------------------------
__global__ void zero_int(int* __restrict__ p, int n) {
  int i = blockIdx.x * blockDim.x + threadIdx.x;
  const int st = gridDim.x * blockDim.x;
  for (; i < n; i += st) p[i] = 0;
}

// exclusive scan within 1024-chunk; chunk totals to tot[dir*128 + chunk]
__global__ __launch_bounds__(1024) void scanA(const int* __restrict__ cnt_u,
                                              const int* __restrict__ cnt_i,
                                              int* ptr_u, int* ptr_i, int* tot) {
  __shared__ int sh[1024];
  const int dir = blockIdx.y;
  const int* cnt = dir ? cnt_i : cnt_u;
  int* ptr = dir ? ptr_i : ptr_u;
  const int t = threadIdx.x;
  const int i = blockIdx.x * 1024 + t;
  const int v = (i < kNU) ? cnt[i] : 0;
  sh[t] = v;
  __syncthreads();
  for (int o = 1; o < 1024; o <<= 1) {
    const int y = (t >= o) ? sh[t - o] : 0;
    __syncthreads();
    sh[t] += y;
    __syncthreads();
  }
  if (i < kNU) ptr[i] = sh[t] - v;  // exclusive within chunk
  if (t == 1023) tot[dir * 128 + blockIdx.x] = sh[1023];
}

// exclusive scan of the (<=98) chunk totals; one block per direction
__global__ __launch_bounds__(128) void scanB(int* tot) {
  __shared__ int sh[128];
  int* tp = tot + blockIdx.x * 128;
  const int t = threadIdx.x;
  const int v = (t < kNCHUNK) ? tp[t] : 0;
  sh[t] = v;
  __syncthreads();
  for (int o = 1; o < 128; o <<= 1) {
    const int y = (t >= o) ? sh[t - o] : 0;
    __syncthreads();
    sh[t] += y;
    __syncthreads();
  }
  if (t < kNCHUNK) tp[t] = sh[t] - v;  // exclusive
}

__global__ __launch_bounds__(1024) void scanC(int* ptr_u, int* ptr_i,
                                              const int* __restrict__ tot,
                                              int* cur_u, int* cur_i) {
  const int dir = blockIdx.y;
  int* ptr = dir ? ptr_i : ptr_u;
  int* cur = dir ? cur_i : cur_u;
  const int i = blockIdx.x * 1024 + threadIdx.x;
  if (i < kNU) {
    const int v = ptr[i] + tot[dir * 128 + blockIdx.x];
    ptr[i] = v;
    cur[i] = v;
  }
}

// ------- projection body: relu(x @ Wp + b) -> fp32, 3-split bf16 MFMA -------
template <int F>
__device__ __forceinline__ void proj_body(
    const float* __restrict__ x, const unsigned short* __restrict__ Wh,
    const unsigned short* __restrict__ Wm, const unsigned short* __restrict__ Wl,
    const float* __restrict__ bias, float* __restrict__ out, int blk,
    unsigned short* sh) {
  constexpr int AS = F + 8, KC = F / 32;
  unsigned short* Ah = sh;
  unsigned short* Am = sh + kM * AS;
  unsigned short* Al = sh + 2 * kM * AS;
  const int tid = threadIdx.x;
  const size_t row0 = (size_t)blk * kM;
  for (int c = tid; c < kM * (F / 4); c += 256) {
    const int r = c / (F / 4), j = c % (F / 4);
    const float4 v = *(const float4*)&x[(row0 + r) * F + j * 4];
    const float* vv = &v.x;
    ushort4v h4, m4, l4;
#pragma unroll
    for (int u = 0; u < 4; ++u) {
      unsigned short th, tm, tl;
      split3(vv[u], th, tm, tl);
      h4[u] = th; m4[u] = tm; l4[u] = tl;
    }
    *(ushort4v*)&Ah[r * AS + j * 4] = h4;
    *(ushort4v*)&Am[r * AS + j * 4] = m4;
    *(ushort4v*)&Al[r * AS + j * 4] = l4;
  }
  const int lane = tid & 63, w = tid >> 6, q = lane >> 4, ln = lane & 15;
  floatx4 acc[2][2] = {}, accL[2][2] = {};
  __syncthreads();
#pragma unroll
  for (int kc = 0; kc < KC; ++kc) {
    bf16x8 bh[2], bm[2], bl_[2];
#pragma unroll
    for (int t = 0; t < 2; ++t) {
      const int off = (w * 32 + t * 16 + ln) * F + kc * 32 + q * 8;
      bh[t] = ldb8(&Wh[off]);
      bm[t] = ldb8(&Wm[off]);
      bl_[t] = ldb8(&Wl[off]);
    }
#pragma unroll
    for (int mt = 0; mt < 2; ++mt) {
      const int ro = mt * 16 + ln, co = kc * 32 + q * 8;
      const bf16x8 ah = ldb8(&Ah[ro * AS + co]);
      const bf16x8 am = ldb8(&Am[ro * AS + co]);
      const bf16x8 al = ldb8(&Al[ro * AS + co]);
#pragma unroll
      for (int t = 0; t < 2; ++t) {
        acc[mt][t] = mfma16(ah, bh[t], acc[mt][t]);  // full scale
        floatx4 cl = accL[mt][t];                    // low-order
        cl = mfma16(ah, bm[t], cl);
        cl = mfma16(am, bh[t], cl);
        cl = mfma16(ah, bl_[t], cl);
        cl = mfma16(al, bh[t], cl);
        cl = mfma16(am, bm[t], cl);
        accL[mt][t] = cl;
      }
    }
  }
#pragma unroll
  for (int t = 0; t < 2; ++t) {
    const int col = w * 32 + t * 16 + ln;
    const float bv = bias[col];
#pragma unroll
    for (int mt = 0; mt < 2; ++mt)
#pragma unroll
      for (int r = 0; r < 4; ++r)
        out[(row0 + mt * 16 + q * 4 + r) * kH + col] =
            fmaxf((acc[mt][t][r] + accL[mt][t][r]) + bv, 0.f);
  }
}

// --- het kernel 1: XCD-partitioned edge-histogram || user-projection --------
__global__ __launch_bounds__(256, 4) void hist_proj(
    const int* __restrict__ eui, const int* __restrict__ eiu, int* cnt_i,
    int* cnt_u, const float* __restrict__ x,
    const unsigned short* __restrict__ Wh, const unsigned short* __restrict__ Wm,
    const unsigned short* __restrict__ Wl, const float* __restrict__ bias,
    float* __restrict__ out) {
  __shared__ __align__(16) unsigned short sh[3 * kM * (kFU + 8)];
  if (blockIdx.x < 8 * kEB) {
    const int part = blockIdx.x & 7, slice = blockIdx.x >> 3;
    const int e = slice * 256 + threadIdx.x;
    if (e < kE) {
      const int di = eui[kE + e];  // dst item
      if (di / kPART == part) atomicAdd(&cnt_i[di], 1);
      const int du = eiu[kE + e];  // dst user
      if (du / kPART == part) atomicAdd(&cnt_u[du], 1);
    }
  } else {  // user projection (F=96)
    proj_body<kFU>(x, Wh, Wm, Wl, bias, out, blockIdx.x - 8 * kEB, sh);
  }
}

// --- het kernel 2: XCD-partitioned CSR fill || item-projection --------------
__global__ __launch_bounds__(256, 4) void fill_proj(
    const int* __restrict__ eui, const int* __restrict__ eiu, int* cur_i,
    int* cur_u, int* __restrict__ col_ui, int* __restrict__ col_iu,
    const float* __restrict__ x, const unsigned short* __restrict__ Wh,
    const unsigned short* __restrict__ Wm, const unsigned short* __restrict__ Wl,
    const float* __restrict__ bias, float* __restrict__ out) {
  __shared__ __align__(16) unsigned short sh[3 * kM * (kFI + 8)];
  if (blockIdx.x < 8 * kEB) {
    const int part = blockIdx.x & 7, slice = blockIdx.x >> 3;
    const int e = slice * 256 + threadIdx.x;
    if (e < kE) {
      const int di = eui[kE + e];
      if (di / kPART == part) {
        const int p = atomicAdd(&cur_i[di], 1);
        col_ui[p] = eui[e];
      }
      const int du = eiu[kE + e];
      if (du / kPART == part) {
        const int p2 = atomicAdd(&cur_u[du], 1);
        col_iu[p2] = eiu[e];
      }
    }
  } else {  // item projection (F=160)
    proj_body<kFI>(x, Wh, Wm, Wl, bias, out, blockIdx.x - 8 * kEB, sh);
  }
}

// ------- gather-mean (fp32), both dirs; fenced 8-deep load batches ----------
struct AggArgs {
  const float* src[2];
  const int* ptr[2];
  const int* cur[2];
  const int* col[2];
  float* out[2];
};
template <int W>
__global__ __launch_bounds__(256) void agg2(AggArgs a) {
  const int dir = blockIdx.y;
  const int w = threadIdx.x >> 6, lane = threadIdx.x & 63;
  const int row = blockIdx.x * 4 + w;
  const float* __restrict__ feat = a.src[dir];
  const int* __restrict__ col = a.col[dir];
  const int beg = a.ptr[dir][row], end = a.cur[dir][row];
  const float inv = 1.0f / fmaxf((float)(end - beg), 1.0f);
  if (W == 128) {
    float s0 = 0.f, s1 = 0.f;
    for (int e = beg; e < end; e += 8) {
      const int n = end - e;  // uniform across wave
      int cidx[8];
#pragma unroll
      for (int j = 0; j < 8; ++j) cidx[j] = col[(j < n) ? (e + j) : e];
      __builtin_amdgcn_sched_barrier(0);
      float2 v[8];
#pragma unroll
      for (int j = 0; j < 8; ++j)
        if (j < n) v[j] = *(const float2*)&feat[(size_t)cidx[j] * 128 + lane * 2];
      __builtin_amdgcn_sched_barrier(0);
#pragma unroll
      for (int j = 0; j < 8; ++j)
        if (j < n) { s0 += v[j].x; s1 += v[j].y; }
    }
    float2 o;
    o.x = s0 * inv;
    o.y = s1 * inv;
    *(float2*)&a.out[dir][(size_t)row * 128 + lane * 2] = o;
  } else {  // W == 64
    float s = 0.f;
    for (int e = beg; e < end; e += 8) {
      const int n = end - e;
      int cidx[8];
#pragma unroll
      for (int j = 0; j < 8; ++j) cidx[j] = col[(j < n) ? (e + j) : e];
      __builtin_amdgcn_sched_barrier(0);
      float v[8];
#pragma unroll
      for (int j = 0; j < 8; ++j)
        if (j < n) v[j] = feat[(size_t)cidx[j] * 64 + lane];
      __builtin_amdgcn_sched_barrier(0);
#pragma unroll
      for (int j = 0; j < 8; ++j)
        if (j < n) s += v[j];
    }
    a.out[dir][(size_t)row * 64 + lane] = s * inv;
  }
}

// --- layer-0 SAGE + fused Z-projection --------------------------------------
// h1 = relu(LN(agg @ WL^T + root @ WR^T + bl)); Z = h1 @ ZB^T (128->64).
// Staging: async global_load_lds of fp32 tiles with pre-swizzled SOURCE
// (rule: DMA writes linear base+lane*16; swizzle applied on the global addr
// and again on the LDS read -> same involution). split2 on the fly.
struct FsArgs {
  const float* agg[2];
  const float* root[2];
  const unsigned short *WLh[2], *WLm[2];
  const unsigned short *WRh[2], *WRm[2];
  const unsigned short *ZBh[2], *ZBm[2];
  const float *bl[2], *g[2], *b[2];
  float* out[2];   // h1
  float* zout[2];  // Z (64-wide), lives in d_out until sage1 overwrites
};
__global__ __launch_bounds__(256, 4) void sage0(FsArgs a) {
  constexpr int NOUT = 128;
  __shared__ __align__(16) char Lds[32768];
  float* Cs = (float*)Lds;  // post-MFMA: [kM][NOUT+1] fp32 (reuses staging)
  const int tid = threadIdx.x;
  const int dir = blockIdx.y;
  const size_t row0 = (size_t)blockIdx.x * kM;
  const float* __restrict__ agg = a.agg[dir];
  const float* __restrict__ root = a.root[dir];
  const unsigned short* __restrict__ WLh = a.WLh[dir];
  const unsigned short* __restrict__ WLm = a.WLm[dir];
  const unsigned short* __restrict__ WRh = a.WRh[dir];
  const unsigned short* __restrict__ WRm = a.WRm[dir];
  const int lane = tid & 63, w = tid >> 6, q = lane >> 4, ln = lane & 15;

  // Async stage: 2 fp32 tiles (16 KB each), 4 x 1KB DMA per wave per tile.
  // Source pre-swizzled: LDS[s] = G[s ^ ((row(s)&7)<<4)], row = s>>9.
  {
    const char* g0 = (const char*)agg + row0 * 512;
    const char* g1 = (const char*)root + row0 * 512;
#pragma unroll
    for (int c = 0; c < 4; ++c) {
      const int sbase = (w * 4 + c) * 1024;
      const int s = sbase + lane * 16;
      const int soff = s ^ (((s >> 9) & 7) << 4);
      gload_lds16(g0 + soff, Lds + sbase);
      gload_lds16(g1 + soff, Lds + 16384 + sbase);
    }
  }

  floatx4 acc[2][2] = {}, accL[2][2] = {};
  __syncthreads();  // drains vmcnt (global_load_lds) for whole block
#pragma unroll
  for (int kc = 0; kc < 4; ++kc) {
    bf16x8 BL[2][2], BR[2][2];
#pragma unroll
    for (int t = 0; t < 2; ++t) {
      const int off = (w * 32 + t * 16 + ln) * kH + kc * 32 + q * 8;
      BL[0][t] = ldb8(&WLh[off]);
      BL[1][t] = ldb8(&WLm[off]);
      BR[0][t] = ldb8(&WRh[off]);
      BR[1][t] = ldb8(&WRm[off]);
    }
#pragma unroll
    for (int mt = 0; mt < 2; ++mt) {
      const int ro = mt * 16 + ln;
      const int lb = ro * 512 + kc * 128 + q * 32;  // logical byte (granule 0)
      const int xr = (ro & 7) << 4;
      const float4 fa0 = *(const float4*)(Lds + (lb ^ xr));
      const float4 fa1 = *(const float4*)(Lds + ((lb + 16) ^ xr));
      const float4 fr0 = *(const float4*)(Lds + 16384 + (lb ^ xr));
      const float4 fr1 = *(const float4*)(Lds + 16384 + ((lb + 16) ^ xr));
      bf16x8 a1h, a1m, a2h, a2m;
      split8(fa0, fa1, a1h, a1m);
      split8(fr0, fr1, a2h, a2m);
#pragma unroll
      for (int t = 0; t < 2; ++t) {
        floatx4 c = acc[mt][t];  // full-scale h*h terms
        c = mfma16(a1h, BL[0][t], c);
        c = mfma16(a2h, BR[0][t], c);
        acc[mt][t] = c;
        floatx4 cl = accL[mt][t];  // low-order terms
        cl = mfma16(a1h, BL[1][t], cl);
        cl = mfma16(a1m, BL[0][t], cl);
        cl = mfma16(a2h, BR[1][t], cl);
        cl = mfma16(a2m, BR[0][t], cl);
        accL[mt][t] = cl;
      }
    }
  }
  __syncthreads();  // done reading staged tiles; reuse Lds as Cs
  const float* __restrict__ blv = a.bl[dir];
#pragma unroll
  for (int t = 0; t < 2; ++t) {
    const int colx = (w * 2 + t) * 16 + ln;
    const float bv = blv[colx];
#pragma unroll
    for (int mt = 0; mt < 2; ++mt)
#pragma unroll
      for (int r = 0; r < 4; ++r)
        Cs[(mt * 16 + q * 4 + r) * (NOUT + 1) + colx] =
            (acc[mt][t][r] + accL[mt][t][r]) + bv;
  }
  __syncthreads();
  // Two-pass LayerNorm: 8 threads/row, 16 cols each; ReLU. Keep h1 in zv[].
  const int r = tid >> 3, sub = tid & 7;
  const float* __restrict__ gg = a.g[dir];
  const float* __restrict__ bb = a.b[dir];
  float vals[16], s = 0.f;
#pragma unroll
  for (int j = 0; j < 16; ++j) {
    const float v = Cs[r * (NOUT + 1) + sub * 16 + j];
    vals[j] = v;
    s += v;
  }
#pragma unroll
  for (int o = 1; o < 8; o <<= 1) s += __shfl_xor(s, o, 64);
  const float mean = s * (1.0f / NOUT);
  float s2 = 0.f;
#pragma unroll
  for (int j = 0; j < 16; ++j) {
    const float d = vals[j] - mean;
    s2 += d * d;
  }
#pragma unroll
  for (int o = 1; o < 8; o <<= 1) s2 += __shfl_xor(s2, o, 64);
  const float rstd = rsqrtf(s2 * (1.0f / NOUT) + kEPS);
  float* op = a.out[dir] + (row0 + r) * NOUT + sub * 16;
  float zv[16];
#pragma unroll
  for (int j = 0; j < 16; j += 4) {
    float4 o4;
    float* oo = &o4.x;
#pragma unroll
    for (int jj = 0; jj < 4; ++jj) {
      const float hv = fmaxf((vals[j + jj] - mean) * rstd * gg[sub * 16 + j + jj] +
                                 bb[sub * 16 + j + jj],
                             0.f);
      oo[jj] = hv;
      zv[j + jj] = hv;
    }
    *(float4*)&op[j] = o4;
  }
  // ---- fused Z = h1 @ ZB^T (128 -> 64): stage h1 planes, 24 MFMAs ----
  __syncthreads();  // Cs dead; reuse Lds[0..16K) for 2 bf16 planes
#pragma unroll
  for (int j = 0; j < 16; j += 8) {
    ushort8v h8, m8;
#pragma unroll
    for (int u = 0; u < 8; ++u) {
      unsigned short th, tm;
      split2(zv[j + u], th, tm);
      h8[u] = th; m8[u] = tm;
    }
    const int bo = sub * 32 + j * 2;  // byte offset in row (16B aligned)
    *(ushort8v*)ab_ptr(Lds, 0, r, bo) = h8;
    *(ushort8v*)ab_ptr(Lds, 1, r, bo) = m8;
  }
  const unsigned short* __restrict__ ZBh = a.ZBh[dir];
  const unsigned short* __restrict__ ZBm = a.ZBm[dir];
  floatx4 zacc[2] = {}, zaccL[2] = {};
  __syncthreads();
#pragma unroll
  for (int kc = 0; kc < 4; ++kc) {
    const int off = (w * 16 + ln) * kH + kc * 32 + q * 8;
    const bf16x8 zbh = ldb8(&ZBh[off]);
    const bf16x8 zbm = ldb8(&ZBm[off]);
#pragma unroll
    for (int mt = 0; mt < 2; ++mt) {
      const int ro = mt * 16 + ln, cob = kc * 64 + q * 16;
      const bf16x8 ah = ldb8(ab_ptr(Lds, 0, ro, cob));
      const bf16x8 am = ldb8(ab_ptr(Lds, 1, ro, cob));
      zacc[mt] = mfma16(ah, zbh, zacc[mt]);
      floatx4 cl = zaccL[mt];
      cl = mfma16(ah, zbm, cl);
      cl = mfma16(am, zbh, cl);
      zaccL[mt] = cl;
    }
  }
  float* __restrict__ zo = a.zout[dir];
  const int zcol = w * 16 + ln;
#pragma unroll
  for (int mt = 0; mt < 2; ++mt)
#pragma unroll
    for (int rr = 0; rr < 4; ++rr)
      zo[(row0 + mt * 16 + q * 4 + rr) * kOUT + zcol] =
          zacc[mt][rr] + zaccL[mt][rr];
}

// --- layer-1 SAGE finish: D = root @ Wr1 + bl + aggz; LN (no ReLU) ----------
struct S1Args {
  const float* root[2];
  const float* aggz[2];
  const unsigned short *Bh[2], *Bm[2];
  const float *bl[2], *g[2], *b[2];
  float* out[2];
};
__global__ __launch_bounds__(256, 5) void sage1(S1Args a) {
  constexpr int NOUT = kOUT;
  __shared__ __align__(16) unsigned short Ab[2 * kM * kH];  // 16 KB
  float* Cs = (float*)Ab;  // reused post-MFMA: [kM][NOUT+1]
  const int tid = threadIdx.x, dir = blockIdx.y;
  const size_t row0 = (size_t)blockIdx.x * kM;
  const float* __restrict__ root = a.root[dir];
  const unsigned short* __restrict__ Bh = a.Bh[dir];
  const unsigned short* __restrict__ Bm = a.Bm[dir];
  const int lane = tid & 63, w = tid >> 6, q = lane >> 4, ln = lane & 15;

  float4 va[4];
#pragma unroll
  for (int k = 0; k < 4; ++k) {
    const int c = tid + k * 256, r = c >> 5, j = c & 31;
    va[k] = *(const float4*)&root[(row0 + r) * kH + j * 4];
  }
  bf16x8 Bh4[4], Bm4[4];
#pragma unroll
  for (int kc = 0; kc < 4; ++kc) {
    const int off = (w * 16 + ln) * kH + kc * 32 + q * 8;
    Bh4[kc] = ldb8(&Bh[off]);
    Bm4[kc] = ldb8(&Bm[off]);
  }
  __builtin_amdgcn_sched_barrier(0);
#pragma unroll
  for (int k = 0; k < 4; ++k) {
    const int c = tid + k * 256, r = c >> 5, j = c & 31;
    const float* vv = &va[k].x;
    ushort4v h4, m4;
#pragma unroll
    for (int u = 0; u < 4; ++u) {
      unsigned short th, tm;
      split2(vv[u], th, tm);
      h4[u] = th; m4[u] = tm;
    }
    *(ushort4v*)ab_ptr(Ab, 0, r, j * 8) = h4;
    *(ushort4v*)ab_ptr(Ab, 1, r, j * 8) = m4;
  }
  floatx4 acc[2] = {}, accL[2] = {};
  __syncthreads();
#pragma unroll
  for (int kc = 0; kc < 4; ++kc) {
#pragma unroll
    for (int mt = 0; mt < 2; ++mt) {
      const int ro = mt * 16 + ln, cob = kc * 64 + q * 16;
      const bf16x8 ah = ldb8(ab_ptr(Ab, 0, ro, cob));
      const bf16x8 am = ldb8(ab_ptr(Ab, 1, ro, cob));
      acc[mt] = mfma16(ah, Bh4[kc], acc[mt]);
      floatx4 cl = accL[mt];
      cl = mfma16(ah, Bm4[kc], cl);
      cl = mfma16(am, Bh4[kc], cl);
      accL[mt] = cl;
    }
  }
  __syncthreads();  // done reading Ab
  const float* __restrict__ blv = a.bl[dir];
  {
    const int col = w * 16 + ln;
    const float bv = blv[col];
#pragma unroll
    for (int mt = 0; mt < 2; ++mt)
#pragma unroll
      for (int r = 0; r < 4; ++r)
        Cs[(mt * 16 + q * 4 + r) * (NOUT + 1) + col] =
            (acc[mt][r] + accL[mt][r]) + bv;
  }
  __syncthreads();
  // LN over 64 cols: 8 threads/row, 8 cols each; add gathered term from global
  const int r = tid >> 3, sub = tid & 7;
  const float* __restrict__ az = a.aggz[dir];
  const float* __restrict__ gg = a.g[dir];
  const float* __restrict__ bb = a.b[dir];
  const float4 az0 = *(const float4*)&az[(row0 + r) * NOUT + sub * 8];
  const float4 az1 = *(const float4*)&az[(row0 + r) * NOUT + sub * 8 + 4];
  float vals[8], s = 0.f;
#pragma unroll
  for (int j = 0; j < 8; ++j) {
    const float v = Cs[r * (NOUT + 1) + sub * 8 + j] +
                    (j < 4 ? (&az0.x)[j] : (&az1.x)[j - 4]);
    vals[j] = v;
    s += v;
  }
#pragma unroll
  for (int o = 1; o < 8; o <<= 1) s += __shfl_xor(s, o, 64);
  const float mean = s * (1.0f / NOUT);
  float s2 = 0.f;
#pragma unroll
  for (int j = 0; j < 8; ++j) {
    const float d = vals[j] - mean;
    s2 += d * d;
  }
#pragma unroll
  for (int o = 1; o < 8; o <<= 1) s2 += __shfl_xor(s2, o, 64);
  const float rstd = rsqrtf(s2 * (1.0f / NOUT) + kEPS);
  float* op = a.out[dir] + (row0 + r) * NOUT + sub * 8;
#pragma unroll
  for (int j = 0; j < 8; j += 4) {
    float4 o4;
    float* oo = &o4.x;
#pragma unroll
    for (int jj = 0; jj < 4; ++jj)
      oo[jj] = (vals[j + jj] - mean) * rstd * gg[sub * 8 + j + jj] +
               bb[sub * 8 + j + jj];
    *(float4*)&op[j] = o4;
  }
}

extern "C" void kernel_launch(void* const* d_in, const int* in_sizes, int n_in,
                              void* d_out, int out_size, void* d_ws, size_t ws_size,
                              hipStream_t stream) {
  (void)in_sizes; (void)n_in; (void)out_size; (void)ws_size;
  const float* x_u    = (const float*)d_in[0];
  const float* x_i    = (const float*)d_in[1];
  const int*   e_ui   = (const int*)d_in[2];
  const int*   e_iu   = (const int*)d_in[3];
  const float* Wp_u   = (const float*)d_in[4];
  const float* bp_u   = (const float*)d_in[5];
  const float* Wp_i   = (const float*)d_in[6];
  const float* bp_i   = (const float*)d_in[7];
  const float* Wl0_ui = (const float*)d_in[8];
  const float* bl0_ui = (const float*)d_in[9];
  const float* Wr0_ui = (const float*)d_in[10];
  const float* Wl0_iu = (const float*)d_in[11];
  const float* bl0_iu = (const float*)d_in[12];
  const float* Wr0_iu = (const float*)d_in[13];
  const float* g0_u   = (const float*)d_in[14];
  const float* b0_u   = (const float*)d_in[15];
  const float* g0_i   = (const float*)d_in[16];
  const float* b0_i   = (const float*)d_in[17];
  const float* Wl1_ui = (const float*)d_in[18];
  const float* bl1_ui = (const float*)d_in[19];
  const float* Wr1_ui = (const float*)d_in[20];
  const float* Wl1_iu = (const float*)d_in[21];
  const float* bl1_iu = (const float*)d_in[22];
  const float* Wr1_iu = (const float*)d_in[23];
  const float* g1_u   = (const float*)d_in[24];
  const float* b1_u   = (const float*)d_in[25];
  const float* g1_i   = (const float*)d_in[26];
  const float* b1_i   = (const float*)d_in[27];

  // ---- workspace layout ----
  float* pf = (float*)d_ws;
  const size_t NH = (size_t)kNU * kH;  // 12.8M floats
  float* hu0 = pf;           // projected user feats
  float* hi0 = pf + NH;      // projected item feats (later: aggzI | aggzU)
  float* b2  = pf + 2 * NH;  // aggI -> h_i1 (in-place)
  float* b3  = pf + 3 * NH;  // aggU -> h_u1 (in-place)
  float* aggzI = hi0;
  float* aggzU = hi0 + (size_t)kNU * kOUT;
  unsigned short* wh = (unsigned short*)(pf + 4 * NH);  // 131072 ushorts each
  unsigned short* wm = wh + 131072;
  unsigned short* wl = wm + 131072;
  int* pi = (int*)(wl + 131072);
  int* cnt_u = pi; pi += kNU;
  int* cnt_i = pi; pi += kNU;
  int* ptr_u = pi; pi += kNU;
  int* ptr_i = pi; pi += kNU;
  int* cur_u = pi; pi += kNU;
  int* cur_i = pi; pi += kNU;
  int* tot   = pi; pi += 2 * 128;
  int* col_ui = pi; pi += kE;
  int* col_iu = pi; pi += kE;

  // weight sub-offsets (identical layout in h/m/l sets)
  const int oPu = 0, oPi = 12288, o0Lui = 32768, o0Rui = 49152,
            o0Liu = 65536, o0Riu = 81920, o1Lui = 98304, o1Rui = 106496,
            o1Liu = 114688, o1Riu = 122880;

  float* out_u = (float*)d_out;               // h_u2: [100000][64]
  float* out_i = out_u + (size_t)kNU * kOUT;  // h_i2: [100000][64]
  // Z buffers live in d_out until sage1 overwrites (agg1 reads them first):
  float* Zu = out_u;  // h_u1 @ Wl1_ui
  float* Zi = out_i;  // h_i1 @ Wl1_iu

  // ---- weight convert/transpose/3-split ----
  WcvtArgs wa;
  const float* wsrc[10] = {Wp_u, Wp_i, Wl0_ui, Wr0_ui, Wl0_iu, Wr0_iu,
                           Wl1_ui, Wr1_ui, Wl1_iu, Wr1_iu};
  const int woff[10] = {oPu, oPi, o0Lui, o0Rui, o0Liu, o0Riu,
                        o1Lui, o1Rui, o1Liu, o1Riu};
  const int wK[10] = {kFU, kFI, kH, kH, kH, kH, kH, kH, kH, kH};
  const int wN[10] = {kH, kH, kH, kH, kH, kH, kOUT, kOUT, kOUT, kOUT};
  for (int i = 0; i < 10; ++i) {
    wa.src[i] = wsrc[i];
    wa.dh[i] = wh + woff[i];
    wa.dm[i] = wm + woff[i];
    wa.dl[i] = wl + woff[i];
    wa.K[i] = wK[i];
    wa.N[i] = wN[i];
  }
  wcvt<<<dim3(80, 10), 256, 0, stream>>>(wa);

  // ---- CSR build (XCD-partitioned) overlapped with projections ----
  zero_int<<<256, 256, 0, stream>>>(cnt_u, 2 * kNU);
  hist_proj<<<8 * kEB + kNBLK, 256, 0, stream>>>(e_ui, e_iu, cnt_i, cnt_u, x_u,
                                                 wh + oPu, wm + oPu, wl + oPu,
                                                 bp_u, hu0);
  scanA<<<dim3(kNCHUNK, 2), 1024, 0, stream>>>(cnt_u, cnt_i, ptr_u, ptr_i, tot);
  scanB<<<2, 128, 0, stream>>>(tot);
  scanC<<<dim3(kNCHUNK, 2), 1024, 0, stream>>>(ptr_u, ptr_i, tot, cur_u, cur_i);
  fill_proj<<<8 * kEB + kNBLK, 256, 0, stream>>>(e_ui, e_iu, cur_i, cur_u,
                                                 col_ui, col_iu, x_i, wh + oPi,
                                                 wm + oPi, wl + oPi, bp_i, hi0);

  // ---- layer 0: gather (both dirs) then SAGE+Zproj (both dirs) ----
  AggArgs g0;
  g0.src[0] = hu0; g0.ptr[0] = ptr_i; g0.cur[0] = cur_i; g0.col[0] = col_ui;
  g0.out[0] = b2;
  g0.src[1] = hi0; g0.ptr[1] = ptr_u; g0.cur[1] = cur_u; g0.col[1] = col_iu;
  g0.out[1] = b3;
  agg2<kH><<<dim3(kNU / 4, 2), 256, 0, stream>>>(g0);

  FsArgs a0;
  a0.agg[0] = b2; a0.root[0] = hi0;
  a0.WLh[0] = wh + o0Lui; a0.WLm[0] = wm + o0Lui;
  a0.WRh[0] = wh + o0Rui; a0.WRm[0] = wm + o0Rui;
  a0.ZBh[0] = wh + o1Liu; a0.ZBm[0] = wm + o1Liu;  // Zi = h_i1 @ Wl1_iu
  a0.bl[0] = bl0_ui; a0.g[0] = g0_i; a0.b[0] = b0_i;
  a0.out[0] = b2;   // h_i1
  a0.zout[0] = Zi;
  a0.agg[1] = b3; a0.root[1] = hu0;
  a0.WLh[1] = wh + o0Liu; a0.WLm[1] = wm + o0Liu;
  a0.WRh[1] = wh + o0Riu; a0.WRm[1] = wm + o0Riu;
  a0.ZBh[1] = wh + o1Lui; a0.ZBm[1] = wm + o1Lui;  // Zu = h_u1 @ Wl1_ui
  a0.bl[1] = bl0_iu; a0.g[1] = g0_u; a0.b[1] = b0_u;
  a0.out[1] = b3;   // h_u1
  a0.zout[1] = Zu;
  sage0<<<dim3(kNBLK, 2), 256, 0, stream>>>(a0);

  // ---- layer 1: gather Z (64-wide), finish ----
  AggArgs g1;
  g1.src[0] = Zu; g1.ptr[0] = ptr_i; g1.cur[0] = cur_i; g1.col[0] = col_ui;
  g1.out[0] = aggzI;
  g1.src[1] = Zi; g1.ptr[1] = ptr_u; g1.cur[1] = cur_u; g1.col[1] = col_iu;
  g1.out[1] = aggzU;
  agg2<kOUT><<<dim3(kNU / 4, 2), 256, 0, stream>>>(g1);

  S1Args s1;
  s1.root[0] = b2; s1.aggz[0] = aggzI;
  s1.Bh[0] = wh + o1Rui; s1.Bm[0] = wm + o1Rui;
  s1.bl[0] = bl1_ui; s1.g[0] = g1_i; s1.b[0] = b1_i; s1.out[0] = out_i;
  s1.root[1] = b3; s1.aggz[1] = aggzU;
  s1.Bh[1] = wh + o1Riu; s1.Bm[1] = wm + o1Riu;
  s1.bl[1] = bl1_iu; s1.g[1] = g1_u; s1.b[1] = b1_u; s1.out[1] = out_u;
  sage1<<<dim3(kNBLK, 2), 256, 0, stream>>>(s1);
}